// Round 2
// baseline (43.773 us; speedup 1.0000x reference)
//
#include <hip/hip_runtime.h>

#define B_ 64
#define T_ 32768
#define NPROT 18
#define NPROLIF 12
#define NLIN 18
#define ROW 22                    // floats per element row
#define BLK 256                   // threads per block
#define F4_PER_BLK (BLK*ROW/4)    // 1408 float4 per block slab

__global__ __launch_bounds__(BLK) void sindy_kernel(
    const float* __restrict__ cand,
    const float* __restrict__ a,
    const float* __restrict__ ss,
    const float* __restrict__ sgn,
    const float* __restrict__ K1p,
    const float* __restrict__ thetap,
    const float* __restrict__ K2p,
    const int* __restrict__ pidx,
    const int* __restrict__ lidx,
    const int* __restrict__ sprop,      // self_propagate as int32 (harness passes integers as int*)
    float* __restrict__ out)
{
    __shared__ float sRow[BLK*ROW];   // 22528 B: raw 22-float rows
    __shared__ float sX[BLK*5];       // 5120 B: per-thread x[4], stride 5 (conflict-free)
    __shared__ uint2 sPP[NPROLIF];    // {packed byte offs, masked coef}
    __shared__ uint4 sLP[NLIN];       // {packed byte offs, masked coef, 500*sign, ss[idx1]}
    __shared__ float sScal[4];        // K1, 1/theta, K2, coef0

    const int tid = threadIdx.x;

    // ---- per-block constant build (runs before the sync) ----
    if (tid < NPROLIF) {
        int i = tid;
        int ia = pidx[i*3+0], ib = pidx[i*3+1], ic = pidx[i*3+2];
        float av = a[1+i];
        bool keep = sprop[1+i] ? (av >= 0.f) : (av <= 0.f);
        unsigned offs = (unsigned)(ia*4) | ((unsigned)(ib*4) << 8) | ((unsigned)(16 + ic*4) << 16);
        sPP[i] = make_uint2(offs, __float_as_uint(keep ? av : 0.f));
    } else if (tid < NPROLIF + NLIN) {           // tids 12..29
        int j = tid - NPROLIF;
        int i0 = lidx[j*2+0], i1 = lidx[j*2+1];
        float av = a[1+NPROLIF+j];
        bool keep = sprop[1+NPROLIF+j] ? (av >= 0.f) : (av <= 0.f);
        unsigned offs = (unsigned)(i0*4) | ((unsigned)(16 + i1*4) << 8);
        sLP[j] = make_uint4(offs,
                            __float_as_uint(keep ? av : 0.f),
                            __float_as_uint(500.f * sgn[j]),
                            __float_as_uint(ss[i1]));
    } else if (tid == NPROLIF + NLIN) {          // tid 30
        float av = a[0];
        bool keep = sprop[0] ? (av >= 0.f) : (av <= 0.f);
        sScal[0] = K1p[0];
        sScal[1] = 1.0f / thetap[0];
        sScal[2] = K2p[0];
        sScal[3] = keep ? av : 0.f;
    }

    // ---- stage the block's candidate slab: fully coalesced float4 copies ----
    const float4* g4 = reinterpret_cast<const float4*>(cand)
                       + (long long)blockIdx.x * F4_PER_BLK;
    float4* s4 = reinterpret_cast<float4*>(sRow);
    #pragma unroll
    for (int k = 0; k < 5; ++k) s4[tid + k*BLK] = g4[tid + k*BLK];
    if (tid < F4_PER_BLK - 5*BLK) s4[tid + 5*BLK] = g4[tid + 5*BLK];   // last 128

    __syncthreads();

    // ---- per-thread row pointers ----
    const char* row = (const char*)&sRow[tid*ROW];   // [con, x0,x1,x2, prot0..17]
    float x0 = sRow[tid*ROW+1], x1 = sRow[tid*ROW+2], x2 = sRow[tid*ROW+3];
    float xs = x0 + x1 + x2;
    float* xr = &sX[tid*5];
    xr[0] = x0; xr[1] = x1; xr[2] = x2; xr[3] = xs;
    const char* xrow = (const char*)xr;

    const float K1 = sScal[0], invTh = sScal[1], K2 = sScal[2];
    float acc = sScal[3] * sRow[tid*ROW+0];          // con term

    #pragma unroll
    for (int i = 0; i < NPROLIF; ++i) {
        uint2 pp = sPP[i];
        float coef = __uint_as_float(pp.y);
        float pA = *(const float*)(xrow + (pp.x & 0xffu));
        float pB = *(const float*)(xrow + ((pp.x >> 8) & 0xffu));
        float pC = *(const float*)(row + (pp.x >> 16));
        float h  = pC * __builtin_amdgcn_rcpf(K1 + pC);
        acc += coef * (pA * (1.0f - pB * invTh) * h);
    }

    #pragma unroll
    for (int j = 0; j < NLIN; ++j) {
        uint4 lp = sLP[j];
        float coef = __uint_as_float(lp.y);
        float A    = __uint_as_float(lp.z);          // 500*sign
        float ssv  = __uint_as_float(lp.w);
        float l0 = *(const float*)(xrow + (lp.x & 0xffu));
        float pr = *(const float*)(row + ((lp.x >> 8) & 0xffu));
        float dp  = pr - ssv;
        float adp = fabsf(dp);
        float h   = adp * __builtin_amdgcn_rcpf(K2 + adp);
        float z   = A * dp - 25.0f;                  // 500*(sign*dp - 0.05)
        float e   = __expf(-z);
        float sig = __builtin_amdgcn_rcpf(1.0f + e);
        acc += coef * (l0 * h * sig);
    }

    out[(long long)blockIdx.x * BLK + tid] = acc;
}

extern "C" void kernel_launch(void* const* d_in, const int* in_sizes, int n_in,
                              void* d_out, int out_size, void* d_ws, size_t ws_size,
                              hipStream_t stream) {
    const float* cand = (const float*)d_in[0];
    const float* a    = (const float*)d_in[1];
    const float* ss   = (const float*)d_in[2];
    const float* sgn  = (const float*)d_in[3];
    const float* K1   = (const float*)d_in[4];
    const float* th   = (const float*)d_in[5];
    const float* K2   = (const float*)d_in[6];
    const int*   pidx = (const int*)d_in[7];
    const int*   lidx = (const int*)d_in[8];
    const int*   sp   = (const int*)d_in[9];
    float* out = (float*)d_out;

    const int nblocks = (B_ * T_) / BLK;   // 8192
    hipLaunchKernelGGL(sindy_kernel, dim3(nblocks), dim3(BLK), 0, stream,
                       cand, a, ss, sgn, K1, th, K2, pidx, lidx, sp, out);
}